// Round 6
// baseline (457.024 us; speedup 1.0000x reference)
//
#include <hip/hip_runtime.h>

// CRF NLL: B=1024, S=512, T=48.
// R10: R9 (MFMA-batched chains, 16 batches/wave, fwd+bwd waves per block)
// with the suspected scratch pathology removed.  R9 measured 2650 cyc/step
// against a ~800-cycle dependence path with VALUBusy 4.5% and VGPR=80 --
// the step lambda took float(&)[4][3] reference params and captured local
// arrays by reference, the classic SROA-defeating pattern (rule #20): state
// likely spilled to scratch, adding ~24 global-latency accesses per step.
// R10 flattens everything: no lambdas, flat W[48] ring (depth 4), flat
// D_[12]/sn_[12], literal indices only after #pragma unroll; exp2f of the
// emission weights computed at refill time (4 steps off the serial path).
// Math, layout, and numerics are byte-identical to R9 (absmax 0.0 proven):
//   wave0 fwd: D_new = (S W? no: S) x E', then *W(dest);  wave1 bwd:
//   D_new = (S*W) x E'^T.  D-layout col=lane&15,row=(lane>>4)*4+reg [m89];
//   A-frags read from LDS 16x48 (stride 72 f16); E' = exp(trans)*2^-8 f16;
//   exact pow2 per-row rescale every 4th step; 60000 clamp before cvt.

#define T 48
#define SLEN 512
#define BATCH 1024
#define NB 16
#define NBLK (BATCH / NB)   // 64 blocks

typedef _Float16 f16x8 __attribute__((ext_vector_type(8)));
typedef float f32x4 __attribute__((ext_vector_type(4)));

__global__ __launch_bounds__(128) void crf_kernel(
    const float* __restrict__ em,      // (B,S,T)
    const int*   __restrict__ tags,    // (B,S)
    const float* __restrict__ mask,    // (B,S)
    const float* __restrict__ trans,   // (T,T)
    const float* __restrict__ start_t, // (T,)
    const float* __restrict__ end_t,   // (T,)
    float*       __restrict__ out)     // scalar
{
    constexpr float LOG2E = 1.4426950408889634f;
    constexpr float LN2   = 0.6931471805599453f;
    constexpr float ESC   = -8.0f;

    const int blk  = blockIdx.x;
    const int tid  = threadIdx.x;
    const int bwd  = tid >> 6;          // wave1 = backward chains
    const int lane = tid & 63;
    const int cl   = lane & 15;         // col-lane
    const int g    = lane >> 4;         // 4-lane-group

    __shared__ __align__(16) _Float16 trbuf[2][16 * 72]; // per-wave 16x48 (+pad)
    __shared__ float cmb[64][17];
    __shared__ float meta[64];          // [0..15] len, [16..31] gold

    {   // zero transpose buffers (pad cols 48..71 stay 0 = MFMA zeros)
        _Float16* tz = &trbuf[0][0];
        for (int i = tid; i < 2 * 16 * 72; i += 128) tz[i] = (_Float16)0.f;
    }

    // ---- lengths of the block's 16 batches ----
    {
        const float* mk = mask + (size_t)(blk * NB + cl) * SLEN;
        float ms = 0.f;
        #pragma unroll
        for (int k = 0; k < SLEN / 16; ++k) {
            const float4 v = *(const float4*)(mk + g * 4 + 16 * k);
            ms += (v.x + v.y) + (v.z + v.w);
        }
        ms += __shfl_xor(ms, 16, 64);
        ms += __shfl_xor(ms, 32, 64);
        if (tid < 16) meta[tid] = ms;
    }
    __syncthreads();

    int len_[4], steps_[4];
    #pragma unroll
    for (int r = 0; r < 4; ++r) {
        const int L = (int)(meta[4 * g + r] + 0.5f);
        len_[r] = L;
        const int nbk = (L - 1) >> 1;
        const int nfk = (L - 1) - nbk;
        steps_[r] = bwd ? nbk : nfk;
    }

    // ---- E' operand fragments (named, resident) ----
    // fwd: B[k][n] = E'[kk][cl+16t];  bwd: B[k][n] = E'[cl+16t .. as kout][kk]
    f16x8 b00, b01, b10, b11, b20, b21;
    #pragma unroll
    for (int t = 0; t < 3; ++t) {
        #pragma unroll
        for (int c = 0; c < 2; ++c) {
            f16x8 v;
            #pragma unroll
            for (int e = 0; e < 8; ++e) {
                const int kk = 32 * c + g * 8 + e;
                float tv = 0.f;
                if (kk < T) {
                    const int idx = bwd ? ((cl + 16 * t) * T + kk)
                                        : (kk * T + (cl + 16 * t));
                    tv = exp2f(trans[idx] * LOG2E + ESC);
                }
                v[e] = (_Float16)tv;
            }
            if (t == 0) { if (c == 0) b00 = v; else b01 = v; }
            if (t == 1) { if (c == 0) b10 = v; else b11 = v; }
            if (t == 2) { if (c == 0) b20 = v; else b21 = v; }
        }
    }

    // ---- per-row bases, state init ----
    const float* bp_[4];
    #pragma unroll
    for (int r = 0; r < 4; ++r)
        bp_[r] = em + (size_t)(blk * NB + 4 * g + r) * (SLEN * T);

    const int dstep = bwd ? -T : T;
    const int omax  = (SLEN - 1) * T;

    float D_[12], sn_[12], Lr_[4], sL_[4];
    #pragma unroll
    for (int r = 0; r < 4; ++r) {
        Lr_[r] = 0.f; sL_[r] = 0.f;
        #pragma unroll
        for (int t = 0; t < 3; ++t) {
            const int ct = cl + 16 * t;
            const float iv = bwd ? exp2f(end_t[ct] * LOG2E)
                                 : exp2f((start_t[ct] + bp_[r][ct]) * LOG2E);
            D_[r * 3 + t] = iv;
            sn_[r * 3 + t] = iv;
        }
    }

    // ---- W ring, depth 4, exp2 applied at refill ----
    float W[48];
    int no_[4];
    #pragma unroll
    for (int r = 0; r < 4; ++r)
        no_[r] = bwd ? (len_[r] - 1) * T : T;
    #pragma unroll
    for (int k = 0; k < 4; ++k) {
        #pragma unroll
        for (int r = 0; r < 4; ++r) {
            int oc = no_[r]; oc = oc < 0 ? 0 : (oc > omax ? omax : oc);
            #pragma unroll
            for (int t = 0; t < 3; ++t)
                W[k * 12 + r * 3 + t] = exp2f(bp_[r][oc + cl + 16 * t] * LOG2E);
            no_[r] += dstep;
        }
    }

    // wave-uniform max step count
    int mx = steps_[0];
    #pragma unroll
    for (int r = 1; r < 4; ++r) mx = steps_[r] > mx ? steps_[r] : mx;
    #pragma unroll
    for (int m = 1; m <= 32; m <<= 1) {
        const int o = __shfl_xor(mx, m, 64);
        mx = o > mx ? o : mx;
    }
    mx = __builtin_amdgcn_readfirstlane(mx);

    _Float16* myt = &trbuf[bwd][0];
    const int wr0 = 4 * g;
    const int rd0 = cl * 72 + g * 8;

    for (int s = 0; s < mx; s += 4) {
        #pragma unroll
        for (int p = 0; p < 4; ++p) {
            // ---- consume W slot p (all indices literal after unroll) ----
            float din[12];
            #pragma unroll
            for (int i = 0; i < 12; ++i)
                din[i] = bwd ? D_[i] * W[p * 12 + i] : D_[i];
            if (p == 3) {          // exact pow2 per-row rescale, cadence s%4==3
                #pragma unroll
                for (int r = 0; r < 4; ++r) {
                    float m = fmaxf(fmaxf(din[r * 3], din[r * 3 + 1]), din[r * 3 + 2]);
                    #pragma unroll
                    for (int mm = 1; mm <= 8; mm <<= 1)
                        m = fmaxf(m, __shfl_xor(m, mm, 64));
                    int e = ((__float_as_int(m) >> 23) & 255) - 127;
                    e = e < -64 ? -64 : e;
                    const float sc = __int_as_float((127 - e) << 23);
                    din[r * 3] *= sc; din[r * 3 + 1] *= sc; din[r * 3 + 2] *= sc;
                    Lr_[r] += (float)e;
                }
            }
            // publish state: clamp, cvt f16, row-major 16x48 (stride 72)
            #pragma unroll
            for (int r = 0; r < 4; ++r)
                #pragma unroll
                for (int t = 0; t < 3; ++t)
                    myt[(wr0 + r) * 72 + (cl + 16 * t)] =
                        (_Float16)fminf(din[r * 3 + t], 60000.f);
            const f16x8 A0 = *(const f16x8*)&myt[rd0];
            const f16x8 A1 = *(const f16x8*)&myt[rd0 + 32];
            f32x4 acc0 = {0.f, 0.f, 0.f, 0.f};
            f32x4 acc1 = {0.f, 0.f, 0.f, 0.f};
            f32x4 acc2 = {0.f, 0.f, 0.f, 0.f};
            acc0 = __builtin_amdgcn_mfma_f32_16x16x32_f16(A0, b00, acc0, 0, 0, 0);
            acc1 = __builtin_amdgcn_mfma_f32_16x16x32_f16(A0, b10, acc1, 0, 0, 0);
            acc2 = __builtin_amdgcn_mfma_f32_16x16x32_f16(A0, b20, acc2, 0, 0, 0);
            acc0 = __builtin_amdgcn_mfma_f32_16x16x32_f16(A1, b01, acc0, 0, 0, 0);
            acc1 = __builtin_amdgcn_mfma_f32_16x16x32_f16(A1, b11, acc1, 0, 0, 0);
            acc2 = __builtin_amdgcn_mfma_f32_16x16x32_f16(A1, b21, acc2, 0, 0, 0);
            const int scur = s + p;
            #pragma unroll
            for (int r = 0; r < 4; ++r) {
                float v0 = acc0[r], v1 = acc1[r], v2 = acc2[r];
                if (!bwd) {
                    v0 *= W[p * 12 + r * 3];
                    v1 *= W[p * 12 + r * 3 + 1];
                    v2 *= W[p * 12 + r * 3 + 2];
                }
                D_[r * 3] = v0; D_[r * 3 + 1] = v1; D_[r * 3 + 2] = v2;
                if (steps_[r] - 1 == scur) {
                    sn_[r * 3] = v0; sn_[r * 3 + 1] = v1; sn_[r * 3 + 2] = v2;
                    sL_[r] = Lr_[r];
                }
            }
            // ---- refill slot p for step scur+4 ----
            #pragma unroll
            for (int r = 0; r < 4; ++r) {
                int oc = no_[r]; oc = oc < 0 ? 0 : (oc > omax ? omax : oc);
                #pragma unroll
                for (int t = 0; t < 3; ++t)
                    W[p * 12 + r * 3 + t] =
                        exp2f(bp_[r][oc + cl + 16 * t] * LOG2E);
                no_[r] += dstep;
            }
        }
    }

    // ---- exchange + gold + combine (as R9, proven) ----
    if (bwd) {
        #pragma unroll
        for (int r = 0; r < 4; ++r) {
            #pragma unroll
            for (int t = 0; t < 3; ++t) cmb[lane][r * 3 + t] = sn_[r * 3 + t];
            cmb[lane][12 + r] = sL_[r];
        }
    } else {
        const int bb = blk * NB + cl;
        const float* eb = em + (size_t)bb * (SLEN * T);
        const int* tb = tags + (size_t)bb * SLEN;
        const int Lb_ = (int)(meta[cl] + 0.5f);
        float gg = 0.f;
        for (int i = 1 + g; i < Lb_; i += 4) {
            const int tc = tb[i], tp = tb[i - 1];
            gg += trans[tc * T + tp] + eb[(size_t)i * T + tc];
        }
        if (g == 0) {
            const int t0 = tb[0], tl = tb[Lb_ - 1];
            gg += start_t[t0] + eb[t0] + end_t[tl];
        }
        gg += __shfl_xor(gg, 16, 64);
        gg += __shfl_xor(gg, 32, 64);
        if (g == 0) meta[16 + cl] = gg;
    }
    __syncthreads();

    if (!bwd) {
        float contrib = 0.f;
        #pragma unroll
        for (int r = 0; r < 4; ++r) {
            float v = sn_[r * 3 + 0] * cmb[lane][r * 3 + 0]
                    + sn_[r * 3 + 1] * cmb[lane][r * 3 + 1]
                    + sn_[r * 3 + 2] * cmb[lane][r * 3 + 2];
            #pragma unroll
            for (int mm = 1; mm <= 8; mm <<= 1) v += __shfl_xor(v, mm, 64);
            const int L = len_[r];
            const int nbk = (L - 1) >> 1;
            const int nfk = (L - 1) - nbk;
            const float fwd = (sL_[r] + cmb[lane][12 + r]
                               + 8.0f * (float)(nfk + nbk) + log2f(v)) * LN2;
            const float gold = meta[16 + 4 * g + r];
            contrib += (fwd - gold);
        }
        contrib *= (1.0f / (float)BATCH);
        contrib = (cl == 0) ? contrib : 0.f;
        #pragma unroll
        for (int m = 1; m <= 32; m <<= 1) contrib += __shfl_xor(contrib, m, 64);
        if (lane == 0) atomicAdd(out, contrib);
    }
}

extern "C" void kernel_launch(void* const* d_in, const int* in_sizes, int n_in,
                              void* d_out, int out_size, void* d_ws, size_t ws_size,
                              hipStream_t stream) {
    const float* em      = (const float*)d_in[0];
    const int*   tags    = (const int*)  d_in[1];
    const float* mask    = (const float*)d_in[2];
    const float* trans   = (const float*)d_in[3];
    const float* start_t = (const float*)d_in[4];
    const float* end_t   = (const float*)d_in[5];
    float* out = (float*)d_out;

    hipMemsetAsync(out, 0, sizeof(float), stream);
    crf_kernel<<<NBLK, 128, 0, stream>>>(em, tags, mask, trans, start_t, end_t, out);
}

// Round 7
// 300.420 us; speedup vs baseline: 1.5213x; 1.5213x over previous
//
#include <hip/hip_runtime.h>

// CRF NLL: B=1024, S=512, T=48.
// R11: transpose-free MFMA recurrence.  R9/R10's step paid a full LDS
// transpose (12 ds_write_b16 + RT + ds_read_b128) because 16x16x32's
// D-layout != A-layout, and R10 additionally serialized a global-load
// latency per step (exp2-at-refill -> vmcnt(0) on the chain).  Fix:
//  - state held TRANSPOSED: St = 48(state) x 16(batch); state is the
//    B-operand, constant E^T tiles are the A-operand (9 f16x4 in VGPRs).
//  - v_mfma_f32_16x16x16_f16 (K=16): B-layout col=lane&15, k=4*(lane>>4)+e
//    == D-layout col=lane&15, row=4*(lane>>4)+reg.  D of step s IS the
//    B K-chunk of step s+1: same lane, same regs.  NO LDS, NO transpose,
//    zero memory ops on the serial cycle: acc -> xW -> clamp/cvt -> mfma.
//  - W ring depth 4, raw float4 loads; exp2 applied ONE STEP before
//    consume (off the load-wait path; vmcnt stays counted).
// fwd wave: St'=Ehat^T x B, W applied post-mfma (dest);  bwd wave:
// W applied pre-mfma (source); Ehat[p][c]=exp(trans[p][c]) per reference
// forward (transitions[prev][curr] in the scan).  Numerics as proven in
// R9/R10 (absmax 0.0): E' = exp(trans)*2^-8 f16, exact pow2 per-batch
// rescale every 4th step, 60000 clamp before every f16 convert.

#define T 48
#define SLEN 512
#define BATCH 1024
#define NB 16
#define NBLK (BATCH / NB)   // 64 blocks

typedef _Float16 f16x4 __attribute__((ext_vector_type(4)));
typedef float f32x4 __attribute__((ext_vector_type(4)));

__global__ __launch_bounds__(128) void crf_kernel(
    const float* __restrict__ em,      // (B,S,T)
    const int*   __restrict__ tags,    // (B,S)
    const float* __restrict__ mask,    // (B,S)
    const float* __restrict__ trans,   // (T,T)
    const float* __restrict__ start_t, // (T,)
    const float* __restrict__ end_t,   // (T,)
    float*       __restrict__ out)     // scalar
{
    constexpr float LOG2E = 1.4426950408889634f;
    constexpr float LN2   = 0.6931471805599453f;
    constexpr float ESC   = -8.0f;

    const int blk  = blockIdx.x;
    const int tid  = threadIdx.x;
    const int bwd  = tid >> 6;          // wave1 = backward chains
    const int lane = tid & 63;
    const int cl   = lane & 15;         // batch index within block
    const int g    = lane >> 4;         // 4-lane group (state-row block)

    __shared__ float cmb[64][13];       // bwd snapshots (12) + sL
    __shared__ float meta[32];          // [0..15] len, [16..31] gold

    // ---- lengths of the block's 16 batches ----
    {
        const float* mk = mask + (size_t)(blk * NB + cl) * SLEN;
        float ms = 0.f;
        #pragma unroll
        for (int k = 0; k < SLEN / 16; ++k) {
            const float4 v = *(const float4*)(mk + g * 4 + 16 * k);
            ms += (v.x + v.y) + (v.z + v.w);
        }
        ms += __shfl_xor(ms, 16, 64);
        ms += __shfl_xor(ms, 32, 64);
        if (tid < 16) meta[tid] = ms;
    }
    __syncthreads();

    const int Lb  = (int)(meta[cl] + 0.5f);
    const int nbk = (Lb - 1) >> 1;
    const int nfk = (Lb - 1) - nbk;
    const int steps = bwd ? nbk : nfk;

    // ---- constant A fragments: 9 tiles (t = output row block, c = K chunk)
    // fwd: A[16t+cl][16c+4g+e] = exp(trans[16c+4g+e][16t+cl]) * 2^-8
    // bwd: transpose of fwd
    f16x4 Af[9];
    #pragma unroll
    for (int t = 0; t < 3; ++t) {
        #pragma unroll
        for (int c = 0; c < 3; ++c) {
            f16x4 v;
            #pragma unroll
            for (int e = 0; e < 4; ++e) {
                const int k   = 16 * c + 4 * g + e;
                const int row = 16 * t + cl;
                const int idx = bwd ? (row * T + k) : (k * T + row);
                v[e] = (_Float16)exp2f(trans[idx] * LOG2E + ESC);
            }
            Af[t * 3 + c] = v;
        }
    }

    // ---- state init: lane (g,cl) holds St[16t+4g+e][cl], t=0..2, e=0..3 ----
    const float* bp = em + (size_t)(blk * NB + cl) * (SLEN * T);
    float D_[12], sn_[12];
    #pragma unroll
    for (int t = 0; t < 3; ++t) {
        const float4 e0 = *(const float4*)(bp + 16 * t + 4 * g);
        #pragma unroll
        for (int e = 0; e < 4; ++e) {
            const int j = 16 * t + 4 * g + e;
            const float ev = (e == 0) ? e0.x : (e == 1) ? e0.y : (e == 2) ? e0.z : e0.w;
            const float iv = bwd ? exp2f(end_t[j] * LOG2E)
                                 : exp2f((start_t[j] + ev) * LOG2E);
            D_[t * 4 + e] = iv;
            sn_[t * 4 + e] = iv;
        }
    }
    float Lr = 0.f, sL = 0.f;

    // ---- W ring: 4 slots x 3 float4, raw em values ----
    const int dstep = bwd ? -T : T;
    const int omax  = (SLEN - 1) * T;
    float4 rg[4][3];
    int no = bwd ? (Lb - 1) * T : T;
    #pragma unroll
    for (int s = 0; s < 4; ++s) {
        int oc = no < 0 ? 0 : (no > omax ? omax : no);
        #pragma unroll
        for (int t = 0; t < 3; ++t)
            rg[s][t] = *(const float4*)(bp + oc + 16 * t + 4 * g);
        no += dstep;
    }
    // staged exp2 of slot 0 (one-time full wait, then pipelined)
    float w_[12];
    #pragma unroll
    for (int t = 0; t < 3; ++t) {
        w_[t * 4 + 0] = exp2f(rg[0][t].x * LOG2E);
        w_[t * 4 + 1] = exp2f(rg[0][t].y * LOG2E);
        w_[t * 4 + 2] = exp2f(rg[0][t].z * LOG2E);
        w_[t * 4 + 3] = exp2f(rg[0][t].w * LOG2E);
    }

    // ---- wave-uniform max step count (steps varies over cl only) ----
    int mx = steps;
    #pragma unroll
    for (int m = 1; m <= 8; m <<= 1) {
        const int o = __shfl_xor(mx, m, 64);
        mx = o > mx ? o : mx;
    }
    mx = __builtin_amdgcn_readfirstlane(mx);

    for (int s = 0; s < mx; s += 4) {
        #pragma unroll
        for (int p = 0; p < 4; ++p) {
            const int scur = s + p;
            // source state for this step (bwd: absorb em at source pos)
            float din[12];
            #pragma unroll
            for (int i = 0; i < 12; ++i)
                din[i] = bwd ? D_[i] * w_[i] : D_[i];
            if (p == 3) {                  // exact pow2 per-batch rescale
                float m = din[0];
                #pragma unroll
                for (int i = 1; i < 12; ++i) m = fmaxf(m, din[i]);
                m = fmaxf(m, __shfl_xor(m, 16, 64));
                m = fmaxf(m, __shfl_xor(m, 32, 64));
                int e = ((__float_as_int(m) >> 23) & 255) - 127;
                e = e < -64 ? -64 : e;
                const float sc = __int_as_float((127 - e) << 23);
                #pragma unroll
                for (int i = 0; i < 12; ++i) din[i] *= sc;
                Lr += (float)e;
            }
            // clamp + cvt: D-regs ARE the next B-frags (identity mapping)
            f16x4 B0, B1, B2;
            #pragma unroll
            for (int e = 0; e < 4; ++e) {
                B0[e] = (_Float16)fminf(din[0 + e], 60000.f);
                B1[e] = (_Float16)fminf(din[4 + e], 60000.f);
                B2[e] = (_Float16)fminf(din[8 + e], 60000.f);
            }
            f32x4 a0 = {0.f, 0.f, 0.f, 0.f};
            f32x4 a1 = {0.f, 0.f, 0.f, 0.f};
            f32x4 a2 = {0.f, 0.f, 0.f, 0.f};
            a0 = __builtin_amdgcn_mfma_f32_16x16x16f16(Af[0], B0, a0, 0, 0, 0);
            a0 = __builtin_amdgcn_mfma_f32_16x16x16f16(Af[1], B1, a0, 0, 0, 0);
            a0 = __builtin_amdgcn_mfma_f32_16x16x16f16(Af[2], B2, a0, 0, 0, 0);
            a1 = __builtin_amdgcn_mfma_f32_16x16x16f16(Af[3], B0, a1, 0, 0, 0);
            a1 = __builtin_amdgcn_mfma_f32_16x16x16f16(Af[4], B1, a1, 0, 0, 0);
            a1 = __builtin_amdgcn_mfma_f32_16x16x16f16(Af[5], B2, a1, 0, 0, 0);
            a2 = __builtin_amdgcn_mfma_f32_16x16x16f16(Af[6], B0, a2, 0, 0, 0);
            a2 = __builtin_amdgcn_mfma_f32_16x16x16f16(Af[7], B1, a2, 0, 0, 0);
            a2 = __builtin_amdgcn_mfma_f32_16x16x16f16(Af[8], B2, a2, 0, 0, 0);
            // new state (+ fwd dest weight), per-batch snapshot at final step
            #pragma unroll
            for (int e = 0; e < 4; ++e) {
                D_[0 + e] = bwd ? a0[e] : a0[e] * w_[0 + e];
                D_[4 + e] = bwd ? a1[e] : a1[e] * w_[4 + e];
                D_[8 + e] = bwd ? a2[e] : a2[e] * w_[8 + e];
            }
            if (steps - 1 == scur) {
                #pragma unroll
                for (int i = 0; i < 12; ++i) sn_[i] = D_[i];
                sL = Lr;
            }
            // stage W for NEXT step (slot loaded >=3 steps ago: counted vmcnt)
            #pragma unroll
            for (int t = 0; t < 3; ++t) {
                const float4 r = rg[(p + 1) & 3][t];
                w_[t * 4 + 0] = exp2f(r.x * LOG2E);
                w_[t * 4 + 1] = exp2f(r.y * LOG2E);
                w_[t * 4 + 2] = exp2f(r.z * LOG2E);
                w_[t * 4 + 3] = exp2f(r.w * LOG2E);
            }
            // refill slot p for step scur+4 (raw loads, no dependent use here)
            {
                int oc = no < 0 ? 0 : (no > omax ? omax : no);
                #pragma unroll
                for (int t = 0; t < 3; ++t)
                    rg[p][t] = *(const float4*)(bp + oc + 16 * t + 4 * g);
                no += dstep;
            }
        }
    }

    // ---- exchange + gold + combine ----
    if (bwd) {
        #pragma unroll
        for (int i = 0; i < 12; ++i) cmb[lane][i] = sn_[i];
        cmb[lane][12] = sL;
    } else {
        // gold path score: batch cl, 4 lanes (g) stride positions
        const int bb = blk * NB + cl;
        const float* eb = em + (size_t)bb * (SLEN * T);
        const int* tb = tags + (size_t)bb * SLEN;
        float gg = 0.f;
        for (int i = 1 + g; i < Lb; i += 4) {
            const int tc = tb[i], tp = tb[i - 1];
            gg += trans[tc * T + tp] + eb[(size_t)i * T + tc];
        }
        if (g == 0) {
            const int t0 = tb[0], tl = tb[Lb - 1];
            gg += start_t[t0] + eb[t0] + end_t[tl];
        }
        gg += __shfl_xor(gg, 16, 64);
        gg += __shfl_xor(gg, 32, 64);
        if (g == 0) meta[16 + cl] = gg;
    }
    __syncthreads();

    if (!bwd) {
        // Z[cl] = sum_j alpha_nf[j] * beta_nf[j]
        float v = 0.f;
        #pragma unroll
        for (int i = 0; i < 12; ++i) v += sn_[i] * cmb[lane][i];
        v += __shfl_xor(v, 16, 64);
        v += __shfl_xor(v, 32, 64);
        const float fwdv = (sL + cmb[lane][12]
                            + 8.0f * (float)(nfk + nbk) + log2f(v)) * LN2;
        float contrib = (g == 0) ? (fwdv - meta[16 + cl]) * (1.0f / (float)BATCH)
                                 : 0.f;
        #pragma unroll
        for (int m = 1; m <= 32; m <<= 1) contrib += __shfl_xor(contrib, m, 64);
        if (lane == 0) atomicAdd(out, contrib);
    }
}

extern "C" void kernel_launch(void* const* d_in, const int* in_sizes, int n_in,
                              void* d_out, int out_size, void* d_ws, size_t ws_size,
                              hipStream_t stream) {
    const float* em      = (const float*)d_in[0];
    const int*   tags    = (const int*)  d_in[1];
    const float* mask    = (const float*)d_in[2];
    const float* trans   = (const float*)d_in[3];
    const float* start_t = (const float*)d_in[4];
    const float* end_t   = (const float*)d_in[5];
    float* out = (float*)d_out;

    hipMemsetAsync(out, 0, sizeof(float), stream);
    crf_kernel<<<NBLK, 128, 0, stream>>>(em, tags, mask, trans, start_t, end_t, out);
}

// Round 8
// 297.887 us; speedup vs baseline: 1.5342x; 1.0085x over previous
//
#include <hip/hip_runtime.h>

// CRF NLL: B=1024, S=512, T=48.
// R12: R11 (transpose-free 16x16x16 MFMA recurrence: state = B-operand,
// D-regs of step s ARE the B K-chunks of step s+1; zero memory ops on the
// serial cycle) with the prefetch pipeline made REAL:
//  - R11 stalled ~1480 cyc/step on vmcnt despite a depth-4 ring because
//    launch_bounds(128) made the allocator (VGPR=76 << ~130 live) shrink
//    load live-ranges -> effective prefetch depth ~0 -> one full load
//    latency per step.  Fix: __launch_bounds__(128, 1) (we never run >2
//    waves/CU) so the ring stays resident in registers.
//  - emission ring depth 4 -> 8 (consume distance 7 steps).
//  - NB 16 -> 8, 128 blocks: 256 waves on 256 CUs (2x outstanding loads,
//    2x active CUs, shorter per-wave makespan).  MFMA B-cols 8..15
//    duplicate cols 0..7 (same addresses, L1 broadcast); gold/combine
//    guarded to cl<8.
//  - refill loads issued at the TOP of each step body; exp2 staging stays
//    one step ahead of consume (off the load-wait path).
// Math byte-identical to R11 (absmax 0.0): E' = exp(trans)*2^-8 f16,
// fwd W post-mfma / bwd W pre-mfma, exact pow2 per-batch rescale every
// 4th step, 60000 clamp before every f16 convert.

#define T 48
#define SLEN 512
#define BATCH 1024
#define NB 8
#define NBLK (BATCH / NB)   // 128 blocks

typedef _Float16 f16x4 __attribute__((ext_vector_type(4)));
typedef float f32x4 __attribute__((ext_vector_type(4)));

__global__ __launch_bounds__(128, 1) void crf_kernel(
    const float* __restrict__ em,      // (B,S,T)
    const int*   __restrict__ tags,    // (B,S)
    const float* __restrict__ mask,    // (B,S)
    const float* __restrict__ trans,   // (T,T)
    const float* __restrict__ start_t, // (T,)
    const float* __restrict__ end_t,   // (T,)
    float*       __restrict__ out)     // scalar
{
    constexpr float LOG2E = 1.4426950408889634f;
    constexpr float LN2   = 0.6931471805599453f;
    constexpr float ESC   = -8.0f;

    const int blk  = blockIdx.x;
    const int tid  = threadIdx.x;
    const int bwd  = tid >> 6;          // wave1 = backward chains
    const int lane = tid & 63;
    const int cl   = lane & 15;         // MFMA column; batch = cl & (NB-1)
    const int cb   = cl & (NB - 1);     // real batch index within block
    const int g    = lane >> 4;         // 4-lane group (state-row block)

    __shared__ float cmb[64][13];       // bwd snapshots (12) + sL
    __shared__ float meta[32];          // [0..15] len, [16..31] gold

    // ---- lengths of the block's batches ----
    {
        const float* mk = mask + (size_t)(blk * NB + cb) * SLEN;
        float ms = 0.f;
        #pragma unroll
        for (int k = 0; k < SLEN / 16; ++k) {
            const float4 v = *(const float4*)(mk + g * 4 + 16 * k);
            ms += (v.x + v.y) + (v.z + v.w);
        }
        ms += __shfl_xor(ms, 16, 64);
        ms += __shfl_xor(ms, 32, 64);
        if (tid < 16) meta[tid] = ms;
    }
    __syncthreads();

    const int Lb  = (int)(meta[cl] + 0.5f);
    const int nbk = (Lb - 1) >> 1;
    const int nfk = (Lb - 1) - nbk;
    const int steps = bwd ? nbk : nfk;

    // ---- constant A fragments: 9 tiles (t = output row block, c = K chunk)
    f16x4 Af[9];
    #pragma unroll
    for (int t = 0; t < 3; ++t) {
        #pragma unroll
        for (int c = 0; c < 3; ++c) {
            f16x4 v;
            #pragma unroll
            for (int e = 0; e < 4; ++e) {
                const int k   = 16 * c + 4 * g + e;
                const int row = 16 * t + cl;
                const int idx = bwd ? (row * T + k) : (k * T + row);
                v[e] = (_Float16)exp2f(trans[idx] * LOG2E + ESC);
            }
            Af[t * 3 + c] = v;
        }
    }

    // ---- state init: lane (g,cl) holds St[16t+4g+e][cl] ----
    const float* bp = em + (size_t)(blk * NB + cb) * (SLEN * T);
    float D_[12], sn_[12];
    #pragma unroll
    for (int t = 0; t < 3; ++t) {
        const float4 e0 = *(const float4*)(bp + 16 * t + 4 * g);
        #pragma unroll
        for (int e = 0; e < 4; ++e) {
            const int j = 16 * t + 4 * g + e;
            const float ev = (e == 0) ? e0.x : (e == 1) ? e0.y : (e == 2) ? e0.z : e0.w;
            const float iv = bwd ? exp2f(end_t[j] * LOG2E)
                                 : exp2f((start_t[j] + ev) * LOG2E);
            D_[t * 4 + e] = iv;
            sn_[t * 4 + e] = iv;
        }
    }
    float Lr = 0.f, sL = 0.f;

    // ---- W ring: 8 slots x 3 float4, raw em values ----
    const int dstep = bwd ? -T : T;
    const int omax  = (SLEN - 1) * T;
    float4 rg[8][3];
    int no = bwd ? (Lb - 1) * T : T;
    #pragma unroll
    for (int s = 0; s < 8; ++s) {
        int oc = no < 0 ? 0 : (no > omax ? omax : no);
        #pragma unroll
        for (int t = 0; t < 3; ++t)
            rg[s][t] = *(const float4*)(bp + oc + 16 * t + 4 * g);
        no += dstep;
    }
    // staged exp2 of slot 0 (one-time full wait, then pipelined)
    float w_[12];
    #pragma unroll
    for (int t = 0; t < 3; ++t) {
        w_[t * 4 + 0] = exp2f(rg[0][t].x * LOG2E);
        w_[t * 4 + 1] = exp2f(rg[0][t].y * LOG2E);
        w_[t * 4 + 2] = exp2f(rg[0][t].z * LOG2E);
        w_[t * 4 + 3] = exp2f(rg[0][t].w * LOG2E);
    }

    // ---- wave-uniform max step count ----
    int mx = steps;
    #pragma unroll
    for (int m = 1; m <= 8; m <<= 1) {
        const int o = __shfl_xor(mx, m, 64);
        mx = o > mx ? o : mx;
    }
    mx = __builtin_amdgcn_readfirstlane(mx);

    for (int s = 0; s < mx; s += 8) {
        #pragma unroll
        for (int p = 0; p < 8; ++p) {
            const int scur = s + p;
            // ---- refill slot p for step scur+8 (issue first, no deps) ----
            {
                int oc = no < 0 ? 0 : (no > omax ? omax : no);
                #pragma unroll
                for (int t = 0; t < 3; ++t)
                    rg[p][t] = *(const float4*)(bp + oc + 16 * t + 4 * g);
                no += dstep;
            }
            // ---- source state for this step (bwd: absorb em at source) ----
            float din[12];
            #pragma unroll
            for (int i = 0; i < 12; ++i)
                din[i] = bwd ? D_[i] * w_[i] : D_[i];
            if ((p & 3) == 3) {            // exact pow2 per-batch rescale
                float m = din[0];
                #pragma unroll
                for (int i = 1; i < 12; ++i) m = fmaxf(m, din[i]);
                m = fmaxf(m, __shfl_xor(m, 16, 64));
                m = fmaxf(m, __shfl_xor(m, 32, 64));
                int e = ((__float_as_int(m) >> 23) & 255) - 127;
                e = e < -64 ? -64 : e;
                const float sc = __int_as_float((127 - e) << 23);
                #pragma unroll
                for (int i = 0; i < 12; ++i) din[i] *= sc;
                Lr += (float)e;
            }
            // clamp + cvt: D-regs ARE the next B-frags (identity mapping)
            f16x4 B0, B1, B2;
            #pragma unroll
            for (int e = 0; e < 4; ++e) {
                B0[e] = (_Float16)fminf(din[0 + e], 60000.f);
                B1[e] = (_Float16)fminf(din[4 + e], 60000.f);
                B2[e] = (_Float16)fminf(din[8 + e], 60000.f);
            }
            f32x4 a0 = {0.f, 0.f, 0.f, 0.f};
            f32x4 a1 = {0.f, 0.f, 0.f, 0.f};
            f32x4 a2 = {0.f, 0.f, 0.f, 0.f};
            a0 = __builtin_amdgcn_mfma_f32_16x16x16f16(Af[0], B0, a0, 0, 0, 0);
            a0 = __builtin_amdgcn_mfma_f32_16x16x16f16(Af[1], B1, a0, 0, 0, 0);
            a0 = __builtin_amdgcn_mfma_f32_16x16x16f16(Af[2], B2, a0, 0, 0, 0);
            a1 = __builtin_amdgcn_mfma_f32_16x16x16f16(Af[3], B0, a1, 0, 0, 0);
            a1 = __builtin_amdgcn_mfma_f32_16x16x16f16(Af[4], B1, a1, 0, 0, 0);
            a1 = __builtin_amdgcn_mfma_f32_16x16x16f16(Af[5], B2, a1, 0, 0, 0);
            a2 = __builtin_amdgcn_mfma_f32_16x16x16f16(Af[6], B0, a2, 0, 0, 0);
            a2 = __builtin_amdgcn_mfma_f32_16x16x16f16(Af[7], B1, a2, 0, 0, 0);
            a2 = __builtin_amdgcn_mfma_f32_16x16x16f16(Af[8], B2, a2, 0, 0, 0);
            // new state (+ fwd dest weight), per-batch snapshot at final step
            #pragma unroll
            for (int e = 0; e < 4; ++e) {
                D_[0 + e] = bwd ? a0[e] : a0[e] * w_[0 + e];
                D_[4 + e] = bwd ? a1[e] : a1[e] * w_[4 + e];
                D_[8 + e] = bwd ? a2[e] : a2[e] * w_[8 + e];
            }
            if (steps - 1 == scur) {
                #pragma unroll
                for (int i = 0; i < 12; ++i) sn_[i] = D_[i];
                sL = Lr;
            }
            // stage W for NEXT step (slot refilled 7 steps ago: counted vmcnt)
            #pragma unroll
            for (int t = 0; t < 3; ++t) {
                const float4 r = rg[(p + 1) & 7][t];
                w_[t * 4 + 0] = exp2f(r.x * LOG2E);
                w_[t * 4 + 1] = exp2f(r.y * LOG2E);
                w_[t * 4 + 2] = exp2f(r.z * LOG2E);
                w_[t * 4 + 3] = exp2f(r.w * LOG2E);
            }
        }
    }

    // ---- exchange + gold + combine ----
    if (bwd) {
        #pragma unroll
        for (int i = 0; i < 12; ++i) cmb[lane][i] = sn_[i];
        cmb[lane][12] = sL;
    } else {
        // gold path score: batch cb, 4 lanes (g) stride positions
        const int bb = blk * NB + cb;
        const float* eb = em + (size_t)bb * (SLEN * T);
        const int* tb = tags + (size_t)bb * SLEN;
        float gg = 0.f;
        for (int i = 1 + g; i < Lb; i += 4) {
            const int tc = tb[i], tp = tb[i - 1];
            gg += trans[tc * T + tp] + eb[(size_t)i * T + tc];
        }
        if (g == 0) {
            const int t0 = tb[0], tl = tb[Lb - 1];
            gg += start_t[t0] + eb[t0] + end_t[tl];
        }
        gg += __shfl_xor(gg, 16, 64);
        gg += __shfl_xor(gg, 32, 64);
        if (g == 0) meta[16 + cl] = gg;
    }
    __syncthreads();

    if (!bwd) {
        // Z[cl] = sum_j alpha_nf[j] * beta_nf[j]
        float v = 0.f;
        #pragma unroll
        for (int i = 0; i < 12; ++i) v += sn_[i] * cmb[lane][i];
        v += __shfl_xor(v, 16, 64);
        v += __shfl_xor(v, 32, 64);
        const float fwdv = (sL + cmb[lane][12]
                            + 8.0f * (float)(nfk + nbk) + log2f(v)) * LN2;
        float contrib = (g == 0 && cl < NB)
                        ? (fwdv - meta[16 + cl]) * (1.0f / (float)BATCH)
                        : 0.f;
        #pragma unroll
        for (int m = 1; m <= 32; m <<= 1) contrib += __shfl_xor(contrib, m, 64);
        if (lane == 0) atomicAdd(out, contrib);
    }
}

extern "C" void kernel_launch(void* const* d_in, const int* in_sizes, int n_in,
                              void* d_out, int out_size, void* d_ws, size_t ws_size,
                              hipStream_t stream) {
    const float* em      = (const float*)d_in[0];
    const int*   tags    = (const int*)  d_in[1];
    const float* mask    = (const float*)d_in[2];
    const float* trans   = (const float*)d_in[3];
    const float* start_t = (const float*)d_in[4];
    const float* end_t   = (const float*)d_in[5];
    float* out = (float*)d_out;

    hipMemsetAsync(out, 0, sizeof(float), stream);
    crf_kernel<<<NBLK, 128, 0, stream>>>(em, tags, mask, trans, start_t, end_t, out);
}

// Round 9
// 264.723 us; speedup vs baseline: 1.7264x; 1.1253x over previous
//
#include <hip/hip_runtime.h>

// CRF NLL: B=1024, S=512, T=48.
// R13: R12 (transpose-free 16x16x16 MFMA recurrence; state = B-operand;
// D-regs of step s ARE the B K-chunks of step s+1) with the prefetch ring
// FORCED resident.  R12's VGPR=108 proved the 8-deep ring (96 VGPRs) was
// not kept in registers: the pressure-aware scheduler sank each refill
// load to its use, exposing a full HBM latency per step (1656 cyc/step =
// 175 issue + 36 mfma + ~1450 load wait).  Fix: sched_barrier(0) at the
// end of every unrolled step body -- loads cannot sink across, 7 barriers
// separate issue from first use, allocator must keep the ring live
// (launch_bounds(128,1) permits ~256 VGPRs).  Within-step scheduling
// stays free (not m141-style full pinning).
// Also: gold-path tail parallelized 4 -> 16 workers/batch across both
// waves (32 iters instead of 128), reduced via shfl + one LDS slot.
// Math byte-identical to R11/R12 (absmax 0.0): E' = exp(trans)*2^-8 f16,
// fwd W post-mfma / bwd W pre-mfma, exact pow2 per-batch rescale every
// 4th step, 60000 clamp before every f16 convert.

#define T 48
#define SLEN 512
#define BATCH 1024
#define NB 8
#define NBLK (BATCH / NB)   // 128 blocks

typedef _Float16 f16x4 __attribute__((ext_vector_type(4)));
typedef float f32x4 __attribute__((ext_vector_type(4)));

__global__ __launch_bounds__(128, 1) void crf_kernel(
    const float* __restrict__ em,      // (B,S,T)
    const int*   __restrict__ tags,    // (B,S)
    const float* __restrict__ mask,    // (B,S)
    const float* __restrict__ trans,   // (T,T)
    const float* __restrict__ start_t, // (T,)
    const float* __restrict__ end_t,   // (T,)
    float*       __restrict__ out)     // scalar
{
    constexpr float LOG2E = 1.4426950408889634f;
    constexpr float LN2   = 0.6931471805599453f;
    constexpr float ESC   = -8.0f;

    const int blk  = blockIdx.x;
    const int tid  = threadIdx.x;
    const int bwd  = tid >> 6;          // wave1 = backward chains
    const int lane = tid & 63;
    const int cl   = lane & 15;         // MFMA column; batch = cl & (NB-1)
    const int cb   = cl & (NB - 1);     // real batch index within block
    const int g    = lane >> 4;         // 4-lane group (state-row block)

    __shared__ float cmb[64][13];       // bwd snapshots (12) + sL
    __shared__ float meta[32];          // [0..15] len, [24..31] bwd gold part

    // ---- lengths of the block's batches ----
    {
        const float* mk = mask + (size_t)(blk * NB + cb) * SLEN;
        float ms = 0.f;
        #pragma unroll
        for (int k = 0; k < SLEN / 16; ++k) {
            const float4 v = *(const float4*)(mk + g * 4 + 16 * k);
            ms += (v.x + v.y) + (v.z + v.w);
        }
        ms += __shfl_xor(ms, 16, 64);
        ms += __shfl_xor(ms, 32, 64);
        if (tid < 16) meta[tid] = ms;
    }
    __syncthreads();

    const int Lb  = (int)(meta[cl] + 0.5f);
    const int nbk = (Lb - 1) >> 1;
    const int nfk = (Lb - 1) - nbk;
    const int steps = bwd ? nbk : nfk;

    // ---- constant A fragments: 9 tiles (t = output row block, c = K chunk)
    f16x4 Af[9];
    #pragma unroll
    for (int t = 0; t < 3; ++t) {
        #pragma unroll
        for (int c = 0; c < 3; ++c) {
            f16x4 v;
            #pragma unroll
            for (int e = 0; e < 4; ++e) {
                const int k   = 16 * c + 4 * g + e;
                const int row = 16 * t + cl;
                const int idx = bwd ? (row * T + k) : (k * T + row);
                v[e] = (_Float16)exp2f(trans[idx] * LOG2E + ESC);
            }
            Af[t * 3 + c] = v;
        }
    }

    // ---- state init: lane (g,cl) holds St[16t+4g+e][cl] ----
    const float* bp = em + (size_t)(blk * NB + cb) * (SLEN * T);
    float D_[12], sn_[12];
    #pragma unroll
    for (int t = 0; t < 3; ++t) {
        const float4 e0 = *(const float4*)(bp + 16 * t + 4 * g);
        #pragma unroll
        for (int e = 0; e < 4; ++e) {
            const int j = 16 * t + 4 * g + e;
            const float ev = (e == 0) ? e0.x : (e == 1) ? e0.y : (e == 2) ? e0.z : e0.w;
            const float iv = bwd ? exp2f(end_t[j] * LOG2E)
                                 : exp2f((start_t[j] + ev) * LOG2E);
            D_[t * 4 + e] = iv;
            sn_[t * 4 + e] = iv;
        }
    }
    float Lr = 0.f, sL = 0.f;

    // ---- W ring: 8 slots x 3 float4, raw em values ----
    const int dstep = bwd ? -T : T;
    const int omax  = (SLEN - 1) * T;
    float4 rg[8][3];
    int no = bwd ? (Lb - 1) * T : T;
    #pragma unroll
    for (int s = 0; s < 8; ++s) {
        int oc = no < 0 ? 0 : (no > omax ? omax : no);
        #pragma unroll
        for (int t = 0; t < 3; ++t)
            rg[s][t] = *(const float4*)(bp + oc + 16 * t + 4 * g);
        no += dstep;
    }
    // staged exp2 of slot 0 (one-time wait, then pipelined)
    float w_[12];
    #pragma unroll
    for (int t = 0; t < 3; ++t) {
        w_[t * 4 + 0] = exp2f(rg[0][t].x * LOG2E);
        w_[t * 4 + 1] = exp2f(rg[0][t].y * LOG2E);
        w_[t * 4 + 2] = exp2f(rg[0][t].z * LOG2E);
        w_[t * 4 + 3] = exp2f(rg[0][t].w * LOG2E);
    }

    // ---- wave-uniform max step count ----
    int mx = steps;
    #pragma unroll
    for (int m = 1; m <= 8; m <<= 1) {
        const int o = __shfl_xor(mx, m, 64);
        mx = o > mx ? o : mx;
    }
    mx = __builtin_amdgcn_readfirstlane(mx);

    for (int s = 0; s < mx; s += 8) {
        #pragma unroll
        for (int p = 0; p < 8; ++p) {
            const int scur = s + p;
            // ---- refill slot p for step scur+8 (issue first, no deps) ----
            {
                int oc = no < 0 ? 0 : (no > omax ? omax : no);
                #pragma unroll
                for (int t = 0; t < 3; ++t)
                    rg[p][t] = *(const float4*)(bp + oc + 16 * t + 4 * g);
                no += dstep;
            }
            // ---- source state for this step (bwd: absorb em at source) ----
            float din[12];
            #pragma unroll
            for (int i = 0; i < 12; ++i)
                din[i] = bwd ? D_[i] * w_[i] : D_[i];
            if ((p & 3) == 3) {            // exact pow2 per-batch rescale
                float m = din[0];
                #pragma unroll
                for (int i = 1; i < 12; ++i) m = fmaxf(m, din[i]);
                m = fmaxf(m, __shfl_xor(m, 16, 64));
                m = fmaxf(m, __shfl_xor(m, 32, 64));
                int e = ((__float_as_int(m) >> 23) & 255) - 127;
                e = e < -64 ? -64 : e;
                const float sc = __int_as_float((127 - e) << 23);
                #pragma unroll
                for (int i = 0; i < 12; ++i) din[i] *= sc;
                Lr += (float)e;
            }
            // clamp + cvt: D-regs ARE the next B-frags (identity mapping)
            f16x4 B0, B1, B2;
            #pragma unroll
            for (int e = 0; e < 4; ++e) {
                B0[e] = (_Float16)fminf(din[0 + e], 60000.f);
                B1[e] = (_Float16)fminf(din[4 + e], 60000.f);
                B2[e] = (_Float16)fminf(din[8 + e], 60000.f);
            }
            f32x4 a0 = {0.f, 0.f, 0.f, 0.f};
            f32x4 a1 = {0.f, 0.f, 0.f, 0.f};
            f32x4 a2 = {0.f, 0.f, 0.f, 0.f};
            a0 = __builtin_amdgcn_mfma_f32_16x16x16f16(Af[0], B0, a0, 0, 0, 0);
            a0 = __builtin_amdgcn_mfma_f32_16x16x16f16(Af[1], B1, a0, 0, 0, 0);
            a0 = __builtin_amdgcn_mfma_f32_16x16x16f16(Af[2], B2, a0, 0, 0, 0);
            a1 = __builtin_amdgcn_mfma_f32_16x16x16f16(Af[3], B0, a1, 0, 0, 0);
            a1 = __builtin_amdgcn_mfma_f32_16x16x16f16(Af[4], B1, a1, 0, 0, 0);
            a1 = __builtin_amdgcn_mfma_f32_16x16x16f16(Af[5], B2, a1, 0, 0, 0);
            a2 = __builtin_amdgcn_mfma_f32_16x16x16f16(Af[6], B0, a2, 0, 0, 0);
            a2 = __builtin_amdgcn_mfma_f32_16x16x16f16(Af[7], B1, a2, 0, 0, 0);
            a2 = __builtin_amdgcn_mfma_f32_16x16x16f16(Af[8], B2, a2, 0, 0, 0);
            // new state (+ fwd dest weight), per-batch snapshot at final step
            #pragma unroll
            for (int e = 0; e < 4; ++e) {
                D_[0 + e] = bwd ? a0[e] : a0[e] * w_[0 + e];
                D_[4 + e] = bwd ? a1[e] : a1[e] * w_[4 + e];
                D_[8 + e] = bwd ? a2[e] : a2[e] * w_[8 + e];
            }
            if (steps - 1 == scur) {
                #pragma unroll
                for (int i = 0; i < 12; ++i) sn_[i] = D_[i];
                sL = Lr;
            }
            // stage W for NEXT step (slot refilled 7 steps ago: counted vmcnt)
            #pragma unroll
            for (int t = 0; t < 3; ++t) {
                const float4 r = rg[(p + 1) & 7][t];
                w_[t * 4 + 0] = exp2f(r.x * LOG2E);
                w_[t * 4 + 1] = exp2f(r.y * LOG2E);
                w_[t * 4 + 2] = exp2f(r.z * LOG2E);
                w_[t * 4 + 3] = exp2f(r.w * LOG2E);
            }
            // pin: nothing (esp. the refill loads) may cross a step boundary
            __builtin_amdgcn_sched_barrier(0);
        }
    }

    // ---- gold partials: 16 workers/batch across BOTH waves (32 iters) ----
    const int bb = blk * NB + cb;
    const float* eb = em + (size_t)bb * (SLEN * T);
    const int*   tb = tags + (size_t)bb * SLEN;
    float gg = 0.f;
    {
        const int worker = bwd * 8 + ((cl >> 3) << 2) + g;   // 0..15
        for (int i = 1 + worker; i < Lb; i += 16) {
            const int tc = tb[i], tp = tb[i - 1];
            gg += trans[tc * T + tp] + eb[(size_t)i * T + tc];
        }
        // reduce over the 8 lanes of this wave sharing batch cb (bits 3,4,5)
        gg += __shfl_xor(gg, 8, 64);
        gg += __shfl_xor(gg, 16, 64);
        gg += __shfl_xor(gg, 32, 64);
    }

    // ---- exchange ----
    if (bwd) {
        #pragma unroll
        for (int i = 0; i < 12; ++i) cmb[lane][i] = sn_[i];
        cmb[lane][12] = sL;
        if (lane == cb) meta[24 + cb] = gg;   // wave1's gold partial
    }
    __syncthreads();

    if (!bwd) {
        // Z[cl] = sum_j alpha_nf[j] * beta_nf[j]
        float v = 0.f;
        #pragma unroll
        for (int i = 0; i < 12; ++i) v += sn_[i] * cmb[lane][i];
        v += __shfl_xor(v, 16, 64);
        v += __shfl_xor(v, 32, 64);
        const float fwdv = (sL + cmb[lane][12]
                            + 8.0f * (float)(nfk + nbk) + log2f(v)) * LN2;
        float contrib = 0.f;
        if (g == 0 && cl < NB) {
            const int t0 = tb[0], tl = tb[Lb - 1];
            const float gold = gg + meta[24 + cl]
                             + start_t[t0] + eb[t0] + end_t[tl];
            contrib = (fwdv - gold) * (1.0f / (float)BATCH);
        }
        #pragma unroll
        for (int m = 1; m <= 32; m <<= 1) contrib += __shfl_xor(contrib, m, 64);
        if (lane == 0) atomicAdd(out, contrib);
    }
}

extern "C" void kernel_launch(void* const* d_in, const int* in_sizes, int n_in,
                              void* d_out, int out_size, void* d_ws, size_t ws_size,
                              hipStream_t stream) {
    const float* em      = (const float*)d_in[0];
    const int*   tags    = (const int*)  d_in[1];
    const float* mask    = (const float*)d_in[2];
    const float* trans   = (const float*)d_in[3];
    const float* start_t = (const float*)d_in[4];
    const float* end_t   = (const float*)d_in[5];
    float* out = (float*)d_out;

    hipMemsetAsync(out, 0, sizeof(float), stream);
    crf_kernel<<<NBLK, 128, 0, stream>>>(em, tags, mask, trans, start_t, end_t, out);
}